// Round 1
// baseline (659.261 us; speedup 1.0000x reference)
//
#include <hip/hip_runtime.h>
#include <hip/hip_bf16.h>

// ---- types ----
typedef __bf16 bf16x8 __attribute__((ext_vector_type(8), may_alias));
typedef float f32x4 __attribute__((ext_vector_type(4)));
typedef unsigned short ushort_a __attribute__((may_alias));

#define MFMA(a, b, c) __builtin_amdgcn_mfma_f32_16x16x32_bf16(a, b, c, 0, 0, 0)

__device__ __forceinline__ unsigned short f2bf(float f) {
  return __builtin_bit_cast(unsigned short, (__bf16)f);
}

// ws element layout (ushort):
//   wfB  [2304][384] @ 0         (884736)
//   wgB  [16][384]   @ 884736    (6144, rows 12..15 zero)
//   waoB [384][384]  @ 890880    (147456)
//   wfoB [384][1536] @ 1038336   (589824)
// total 1628160 elements = 3,256,320 bytes

__global__ __launch_bounds__(256) void prep_weights(
    const float* __restrict__ wf, const float* __restrict__ wg,
    const float* __restrict__ wao, const float* __restrict__ wfo,
    unsigned short* __restrict__ ws) {
  int i = blockIdx.x * 256 + threadIdx.x;
  if (i < 884736) { ws[i] = f2bf(wf[i]); return; }
  int j = i - 884736;
  if (j < 6144) { ws[i] = f2bf(j < 4608 ? wg[j] : 0.0f); return; }
  j -= 6144;
  if (j < 147456) { ws[i] = f2bf(wao[j]); return; }
  j -= 147456;
  if (j < 589824) ws[i] = f2bf(wfo[j]);
}

// LDS layout (bytes), 147456 total:
//   As  [64][384] bf16 row-swz      @ 0       (49152)
//   Xg  [64][384] bf16 row-swz      @ 49152   (49152)
//   per-wave attn buffers           @ 98304 + wave*12288:
//       Qb [64][32], Kb [64][32], KTb [32][64]; P [64][64] overlays Qb+Kb
//   F tiles (phase 2) alias attn region: fb = 98304 + (t&1)*16384

__global__ __launch_bounds__(256, 1) void fused_main(
    const float* __restrict__ x,
    const float* __restrict__ bgate,
    const float* __restrict__ srs,
    const float* __restrict__ srb,
    const unsigned short* __restrict__ wsb,
    float* __restrict__ out) {
  const unsigned short* wfB  = wsb;
  const unsigned short* wgB  = wsb + 884736;
  const unsigned short* waoB = wsb + 890880;
  const unsigned short* wfoB = wsb + 1038336;

  __shared__ __align__(16) char smem[147456];
  char* As = smem;
  char* Xg = smem + 49152;

  const int tid = threadIdx.x;
  const int lane = tid & 63, wave = tid >> 6;
  const int l15 = lane & 15, l4 = lane >> 4;

  char* PW  = smem + 98304 + wave * 12288;
  char* Qb  = PW;
  char* Kb  = PW + 4096;
  char* KTb = PW + 8192;
  char* Pb  = PW;  // overlays Qb+Kb (8 KB)

  // XCD swizzle: consecutive windows (which share x/out cache lines) on one XCD
  const int g  = blockIdx.x;
  const int wi = (g & 7) * 128 + (g >> 3);
  const int b = wi >> 6, ghi = (wi >> 3) & 7, gwi = wi & 7;
  const int h0 = ghi * 8, w0 = gwi * 8;

  // ---- gather window -> LDS bf16 [64 tok][384 ch], XOR row-swizzled ----
  {
    const float* xb = x + (size_t)b * 1572864 + h0 * 64 + w0;
    for (int it = 0; it < 12; ++it) {
      int idx = it * 256 + tid;           // [0, 3072): (c, p1) pairs
      int c = idx % 384, p1 = idx / 384;
      const float* src = xb + (size_t)c * 4096 + p1 * 64;
      float4 v0 = *(const float4*)src;
      float4 v1 = *(const float4*)(src + 4);
      float f[8] = {v0.x, v0.y, v0.z, v0.w, v1.x, v1.y, v1.z, v1.w};
#pragma unroll
      for (int jj = 0; jj < 8; ++jj) {
        int row = p1 * 8 + jj;            // token
        int byte = (row * 768 + c * 2) ^ ((row & 7) << 4);
        *(ushort_a*)(As + byte) = f2bf(f[jj]);
      }
    }
  }
  const float ss = srs[0], sbi = srb[0];
  __syncthreads();

  auto ldA = [&](int row, int ks) -> bf16x8 {
    int byte = (row * 768 + ks * 64 + l4 * 16) ^ ((row & 7) << 4);
    return *(const bf16x8*)(As + byte);
  };

  // ---- gate GEMM: G[n][h] = A·wgBᵀ (each wave computes full 16-col tile) ----
  f32x4 gfr[4] = {};
  {
    const unsigned short* wg0 = wgB + (size_t)l15 * 384 + l4 * 8;
#pragma unroll 2
    for (int ks = 0; ks < 12; ++ks) {
      bf16x8 bg = *(const bf16x8*)(wg0 + ks * 32);
      bf16x8 a0 = ldA(l15, ks), a1 = ldA(16 + l15, ks),
             a2 = ldA(32 + l15, ks), a3 = ldA(48 + l15, ks);
      gfr[0] = MFMA(a0, bg, gfr[0]);
      gfr[1] = MFMA(a1, bg, gfr[1]);
      gfr[2] = MFMA(a2, bg, gfr[2]);
      gfr[3] = MFMA(a3, bg, gfr[3]);
    }
    float gb = (l15 < 12) ? bgate[l15] : 0.0f;
#pragma unroll
    for (int mt = 0; mt < 4; ++mt) gfr[mt] += gb;
  }

  // ---- phase 1: per-wave heads (3 each) ----
#pragma unroll 1
  for (int hi = 0; hi < 3; ++hi) {
    const int h = wave * 3 + hi;
    f32x4 qf[4][2] = {}, kf[4][2] = {};
    const unsigned short* wq = wfB + ((size_t)(h * 32) + l15) * 384 + l4 * 8;
    const unsigned short* wk = wq + (size_t)384 * 384;
#pragma unroll 2
    for (int ks = 0; ks < 12; ++ks) {
      bf16x8 a0 = ldA(l15, ks), a1 = ldA(16 + l15, ks),
             a2 = ldA(32 + l15, ks), a3 = ldA(48 + l15, ks);
#pragma unroll
      for (int nt = 0; nt < 2; ++nt) {
        bf16x8 bq = *(const bf16x8*)(wq + (size_t)nt * 16 * 384 + ks * 32);
        bf16x8 bk = *(const bf16x8*)(wk + (size_t)nt * 16 * 384 + ks * 32);
        qf[0][nt] = MFMA(a0, bq, qf[0][nt]);
        qf[1][nt] = MFMA(a1, bq, qf[1][nt]);
        qf[2][nt] = MFMA(a2, bq, qf[2][nt]);
        qf[3][nt] = MFMA(a3, bq, qf[3][nt]);
        kf[0][nt] = MFMA(a0, bk, kf[0][nt]);
        kf[1][nt] = MFMA(a1, bk, kf[1][nt]);
        kf[2][nt] = MFMA(a2, bk, kf[2][nt]);
        kf[3][nt] = MFMA(a3, bk, kf[3][nt]);
      }
    }
    // write q (pre-scaled), kv row-major, kvT
#pragma unroll
    for (int mt = 0; mt < 4; ++mt)
#pragma unroll
      for (int nt = 0; nt < 2; ++nt)
#pragma unroll
        for (int r = 0; r < 4; ++r) {
          int n = mt * 16 + l4 * 4 + r;
          int d = nt * 16 + l15;
          *(ushort_a*)(Qb + ((n * 64 + d * 2) ^ ((n & 3) << 4))) =
              f2bf(qf[mt][nt][r] * 0.176776695f);
          unsigned short kvv = f2bf(kf[mt][nt][r]);
          *(ushort_a*)(Kb + ((n * 64 + d * 2) ^ ((n & 3) << 4))) = kvv;
          *(ushort_a*)(KTb + ((d * 128 + n * 2) ^ ((d & 7) << 4))) = kvv;
        }
    // scores S[n][m] (K=32, one MFMA per tile pair)
    f32x4 sf[4][4] = {};
    {
      bf16x8 bkv[4];
#pragma unroll
      for (int ni = 0; ni < 4; ++ni) {
        int m = ni * 16 + l15;
        bkv[ni] = *(const bf16x8*)(Kb + ((m * 64 + l4 * 16) ^ ((m & 3) << 4)));
      }
#pragma unroll
      for (int mt = 0; mt < 4; ++mt) {
        int n = mt * 16 + l15;
        bf16x8 aq = *(const bf16x8*)(Qb + ((n * 64 + l4 * 16) ^ ((n & 3) << 4)));
#pragma unroll
        for (int ni = 0; ni < 4; ++ni) sf[mt][ni] = MFMA(aq, bkv[ni], sf[mt][ni]);
      }
    }
    // softmax over m (in-reg across 4 ni + shfl over 16-lane col groups), write P
#pragma unroll
    for (int mt = 0; mt < 4; ++mt) {
#pragma unroll
      for (int r = 0; r < 4; ++r) {
        float v0 = sf[mt][0][r], v1 = sf[mt][1][r], v2 = sf[mt][2][r], v3 = sf[mt][3][r];
        float mx = fmaxf(fmaxf(v0, v1), fmaxf(v2, v3));
        mx = fmaxf(mx, __shfl_xor(mx, 1, 64));
        mx = fmaxf(mx, __shfl_xor(mx, 2, 64));
        mx = fmaxf(mx, __shfl_xor(mx, 4, 64));
        mx = fmaxf(mx, __shfl_xor(mx, 8, 64));
        float e0 = __expf(v0 - mx), e1 = __expf(v1 - mx),
              e2 = __expf(v2 - mx), e3 = __expf(v3 - mx);
        float sm = e0 + e1 + e2 + e3;
        sm += __shfl_xor(sm, 1, 64);
        sm += __shfl_xor(sm, 2, 64);
        sm += __shfl_xor(sm, 4, 64);
        sm += __shfl_xor(sm, 8, 64);
        float rs = 1.0f / sm;
        int n = mt * 16 + l4 * 4 + r;
        int base = n * 128, swz = (n & 7) << 4;
        *(ushort_a*)(Pb + ((base + l15 * 2) ^ swz))      = f2bf(e0 * rs);
        *(ushort_a*)(Pb + ((base + 32 + l15 * 2) ^ swz)) = f2bf(e1 * rs);
        *(ushort_a*)(Pb + ((base + 64 + l15 * 2) ^ swz)) = f2bf(e2 * rs);
        *(ushort_a*)(Pb + ((base + 96 + l15 * 2) ^ swz)) = f2bf(e3 * rs);
      }
    }
    // PV: X[n][d] = P·kv  (K=64 -> 2 ksteps)
    f32x4 xo[4][2] = {};
#pragma unroll
    for (int ks = 0; ks < 2; ++ks) {
      bf16x8 bv[2];
#pragma unroll
      for (int nt = 0; nt < 2; ++nt) {
        int d = nt * 16 + l15;
        bv[nt] = *(const bf16x8*)(KTb + ((d * 128 + ks * 64 + l4 * 16) ^ ((d & 7) << 4)));
      }
#pragma unroll
      for (int mt = 0; mt < 4; ++mt) {
        int n = mt * 16 + l15;
        bf16x8 ap = *(const bf16x8*)(Pb + ((n * 128 + ks * 64 + l4 * 16) ^ ((n & 7) << 4)));
        xo[mt][0] = MFMA(ap, bv[0], xo[mt][0]);
        xo[mt][1] = MFMA(ap, bv[1], xo[mt][1]);
      }
    }
    // gate (shuffle from gate fragments) + write gated x_attn into Xg
#pragma unroll
    for (int mt = 0; mt < 4; ++mt) {
#pragma unroll
      for (int r = 0; r < 4; ++r) {
        float gv = __shfl(gfr[mt][r], (lane & 48) | h, 64);
        float sg = 1.0f / (1.0f + __expf(-gv));
        int n = mt * 16 + l4 * 4 + r;
        int swz = (n & 7) << 4;
        int c0 = h * 32 + l15;
        *(ushort_a*)(Xg + ((n * 768 + c0 * 2) ^ swz))        = f2bf(xo[mt][0][r] * sg);
        *(ushort_a*)(Xg + ((n * 768 + (c0 + 16) * 2) ^ swz)) = f2bf(xo[mt][1][r] * sg);
      }
    }
  }
  __syncthreads();

  // ---- phase 2c: out = Xg · waoᵀ (per wave: 96 output cols) ----
  f32x4 of[4][6] = {};
  {
    const unsigned short* wao0 = waoB + (size_t)(wave * 96 + l15) * 384 + l4 * 8;
#pragma unroll 2
    for (int ks = 0; ks < 12; ++ks) {
      int kb = ks * 64 + l4 * 16, sz = (l15 & 7) << 4;
      bf16x8 a0 = *(const bf16x8*)(Xg + (((l15)*768 + kb) ^ sz));
      bf16x8 a1 = *(const bf16x8*)(Xg + (((16 + l15) * 768 + kb) ^ sz));
      bf16x8 a2 = *(const bf16x8*)(Xg + (((32 + l15) * 768 + kb) ^ sz));
      bf16x8 a3 = *(const bf16x8*)(Xg + (((48 + l15) * 768 + kb) ^ sz));
#pragma unroll
      for (int nt = 0; nt < 6; ++nt) {
        bf16x8 bw = *(const bf16x8*)(wao0 + (size_t)nt * 16 * 384 + ks * 32);
        of[0][nt] = MFMA(a0, bw, of[0][nt]);
        of[1][nt] = MFMA(a1, bw, of[1][nt]);
        of[2][nt] = MFMA(a2, bw, of[2][nt]);
        of[3][nt] = MFMA(a3, bw, of[3][nt]);
      }
    }
  }

  // ---- phase 2a/2b: 12 F-tiles of 128 cols, StarReLU, out += F · wfoᵀ ----
#pragma unroll 1
  for (int t = 0; t < 12; ++t) {
    f32x4 ffr[4][2] = {};
    const unsigned short* wfin =
        wfB + (size_t)(768 + t * 128 + wave * 32 + l15) * 384 + l4 * 8;
#pragma unroll 2
    for (int ks = 0; ks < 12; ++ks) {
      bf16x8 a0 = ldA(l15, ks), a1 = ldA(16 + l15, ks),
             a2 = ldA(32 + l15, ks), a3 = ldA(48 + l15, ks);
#pragma unroll
      for (int nt = 0; nt < 2; ++nt) {
        bf16x8 bw = *(const bf16x8*)(wfin + (size_t)nt * 16 * 384 + ks * 32);
        ffr[0][nt] = MFMA(a0, bw, ffr[0][nt]);
        ffr[1][nt] = MFMA(a1, bw, ffr[1][nt]);
        ffr[2][nt] = MFMA(a2, bw, ffr[2][nt]);
        ffr[3][nt] = MFMA(a3, bw, ffr[3][nt]);
      }
    }
    char* fb = smem + 98304 + (t & 1) * 16384;  // [64][128] bf16, row-swz
#pragma unroll
    for (int mt = 0; mt < 4; ++mt)
#pragma unroll
      for (int nt = 0; nt < 2; ++nt)
#pragma unroll
        for (int r = 0; r < 4; ++r) {
          float v = fmaxf(ffr[mt][nt][r], 0.0f);
          v = ss * v * v + sbi;  // StarReLU
          int n = mt * 16 + l4 * 4 + r;
          int col = wave * 32 + nt * 16 + l15;
          *(ushort_a*)(fb + ((n * 256 + col * 2) ^ ((n & 7) << 4))) = f2bf(v);
        }
    __syncthreads();
    const unsigned short* wfo2 =
        wfoB + (size_t)(wave * 96 + l15) * 1536 + t * 128 + l4 * 8;
#pragma unroll
    for (int ks = 0; ks < 4; ++ks) {
      int kb = ks * 64 + l4 * 16, sz = (l15 & 7) << 4;
      bf16x8 a0 = *(const bf16x8*)(fb + (((l15)*256 + kb) ^ sz));
      bf16x8 a1 = *(const bf16x8*)(fb + (((16 + l15) * 256 + kb) ^ sz));
      bf16x8 a2 = *(const bf16x8*)(fb + (((32 + l15) * 256 + kb) ^ sz));
      bf16x8 a3 = *(const bf16x8*)(fb + (((48 + l15) * 256 + kb) ^ sz));
#pragma unroll
      for (int nt = 0; nt < 6; ++nt) {
        bf16x8 bw = *(const bf16x8*)(wfo2 + (size_t)nt * 16 * 1536 + ks * 32);
        of[0][nt] = MFMA(a0, bw, of[0][nt]);
        of[1][nt] = MFMA(a1, bw, of[1][nt]);
        of[2][nt] = MFMA(a2, bw, of[2][nt]);
        of[3][nt] = MFMA(a3, bw, of[3][nt]);
      }
    }
  }

  // ---- epilogue: scatter out (fp32, NCHW) ----
  float* ob = out + (size_t)b * 1572864 + h0 * 64 + w0;
#pragma unroll
  for (int nt = 0; nt < 6; ++nt) {
    int col = wave * 96 + nt * 16 + l15;
    float* oc = ob + (size_t)col * 4096;
#pragma unroll
    for (int mt = 0; mt < 4; ++mt) {
#pragma unroll
      for (int r = 0; r < 4; ++r) {
        int n = mt * 16 + l4 * 4 + r;
        oc[(n >> 3) * 64 + (n & 7)] = of[mt][nt][r];
      }
    }
  }
}

extern "C" void kernel_launch(void* const* d_in, const int* in_sizes, int n_in,
                              void* d_out, int out_size, void* d_ws, size_t ws_size,
                              hipStream_t stream) {
  const float* x   = (const float*)d_in[0];
  const float* wf  = (const float*)d_in[1];
  const float* wg  = (const float*)d_in[2];
  const float* bg  = (const float*)d_in[3];
  const float* wao = (const float*)d_in[4];
  const float* wfo = (const float*)d_in[5];
  const float* srs = (const float*)d_in[6];
  const float* srb = (const float*)d_in[7];
  unsigned short* ws = (unsigned short*)d_ws;

  prep_weights<<<6360, 256, 0, stream>>>(wf, wg, wao, wfo, ws);
  fused_main<<<1024, 256, 0, stream>>>(x, bg, srs, srb, ws, (float*)d_out);
}

// Round 2
// 563.800 us; speedup vs baseline: 1.1693x; 1.1693x over previous
//
#include <hip/hip_runtime.h>
#include <hip/hip_bf16.h>

// ---- types ----
typedef __bf16 bf16x8 __attribute__((ext_vector_type(8), may_alias));
typedef float f32x4 __attribute__((ext_vector_type(4), may_alias));
typedef unsigned short ushort_a __attribute__((may_alias));

#define MFMA(a, b, c) __builtin_amdgcn_mfma_f32_16x16x32_bf16(a, b, c, 0, 0, 0)

__device__ __forceinline__ unsigned short f2bf(float f) {
  return __builtin_bit_cast(unsigned short, (__bf16)f);
}

// ws element layout (ushort):
//   wfB  [2304][384] @ 0         (884736)
//   wgB  [16][384]   @ 884736    (6144, rows 12..15 zero)
//   waoB [384][384]  @ 890880    (147456)
//   wfoB [384][1536] @ 1038336   (589824)

__global__ __launch_bounds__(256) void prep_weights(
    const float* __restrict__ wf, const float* __restrict__ wg,
    const float* __restrict__ wao, const float* __restrict__ wfo,
    unsigned short* __restrict__ ws) {
  int i = blockIdx.x * 256 + threadIdx.x;
  if (i < 884736) { ws[i] = f2bf(wf[i]); return; }
  int j = i - 884736;
  if (j < 6144) { ws[i] = f2bf(j < 4608 ? wg[j] : 0.0f); return; }
  j -= 6144;
  if (j < 147456) { ws[i] = f2bf(wao[j]); return; }
  j -= 147456;
  if (j < 589824) ws[i] = f2bf(wfo[j]);
}

// LDS layout (bytes), 114688 total:
//   As   [64][384] bf16 row-swz        @ 0       (49152)
//   pair regions (4 x 12288)           @ 49152   (49152)
//       QK [64 rows][128B: Q|K] swz, P overlays; KTb [32][64] @ +8192
//   F tiles (FF phase) alias pair rgn: fb = 49152 + (t&1)*16384
//   Stg  [64][128] bf16 row-swz        @ 98304   (16384)

__global__ __launch_bounds__(512, 2) void fused_main(
    const float* __restrict__ x,
    const float* __restrict__ bgate,
    const float* __restrict__ srs,
    const float* __restrict__ srb,
    const unsigned short* __restrict__ wsb,
    float* __restrict__ out) {
  const unsigned short* wfB  = wsb;
  const unsigned short* wgB  = wsb + 884736;
  const unsigned short* waoB = wsb + 890880;
  const unsigned short* wfoB = wsb + 1038336;

  __shared__ __align__(16) char smem[114688];
  char* As  = smem;
  char* Stg = smem + 98304;

  const int tid = threadIdx.x;
  const int lane = tid & 63, wave = tid >> 6;
  const int l15 = lane & 15, l4 = lane >> 4;
  const int pair = wave >> 1, nb = (wave & 1) * 32;
  char* PB  = smem + 49152 + pair * 12288;  // QK rows, later P
  char* KTb = PB + 8192;                    // [32 d][64 m]

  // XCD swizzle: consecutive windows (sharing x/out cache lines) on one XCD
  const int g  = blockIdx.x;
  const int wi = (g & 7) * 128 + (g >> 3);
  const int b = wi >> 6, ghi = (wi >> 3) & 7, gwi = wi & 7;
  const int h0 = ghi * 8, w0 = gwi * 8;

  // ---- gather window -> LDS bf16 [64 tok][384 ch], XOR row-swizzled ----
  {
    const float* xb = x + (size_t)b * 1572864 + h0 * 64 + w0;
    for (int it = 0; it < 6; ++it) {
      int idx = it * 512 + tid;           // [0, 3072): (c, p1) pairs
      int c = idx % 384, p1 = idx / 384;
      const float* src = xb + (size_t)c * 4096 + p1 * 64;
      float4 v0 = *(const float4*)src;
      float4 v1 = *(const float4*)(src + 4);
      float f[8] = {v0.x, v0.y, v0.z, v0.w, v1.x, v1.y, v1.z, v1.w};
#pragma unroll
      for (int jj = 0; jj < 8; ++jj) {
        int row = p1 * 8 + jj;            // token
        int byte = (row * 768 + c * 2) ^ ((row & 7) << 4);
        *(ushort_a*)(As + byte) = f2bf(f[jj]);
      }
    }
  }
  const float ss = srs[0], sbi = srb[0];
  __syncthreads();

  auto ldA = [&](int row, int ks) -> bf16x8 {
    int byte = (row * 768 + ks * 64 + l4 * 16) ^ ((row & 7) << 4);
    return *(const bf16x8*)(As + byte);
  };

  // ---- gate GEMM over own half rows: G[n][h] ----
  f32x4 gfr[2] = {};
  {
    const unsigned short* wg0 = wgB + (size_t)l15 * 384 + l4 * 8;
#pragma unroll 2
    for (int ks = 0; ks < 12; ++ks) {
      bf16x8 bg = *(const bf16x8*)(wg0 + ks * 32);
      bf16x8 a0 = ldA(nb + l15, ks), a1 = ldA(nb + 16 + l15, ks);
      gfr[0] = MFMA(a0, bg, gfr[0]);
      gfr[1] = MFMA(a1, bg, gfr[1]);
    }
    float gb = (l15 < 12) ? bgate[l15] : 0.0f;
    gfr[0] += gb;
    gfr[1] += gb;
  }

  f32x4 of[4][3] = {};  // 48 out cols per wave, accumulated attn-out + FF-out

  // ---- attention: 3 rounds x 4 heads (one head per pair, half rows per wave)
#pragma unroll 1
  for (int r = 0; r < 3; ++r) {
    const int h = r * 4 + pair;
    // QKV GEMM for own half rows
    f32x4 qf[2][2] = {}, kf[2][2] = {};
    const unsigned short* wq = wfB + ((size_t)(h * 32) + l15) * 384 + l4 * 8;
    const unsigned short* wk = wq + (size_t)384 * 384;
#pragma unroll 2
    for (int ks = 0; ks < 12; ++ks) {
      bf16x8 a0 = ldA(nb + l15, ks), a1 = ldA(nb + 16 + l15, ks);
#pragma unroll
      for (int nt = 0; nt < 2; ++nt) {
        bf16x8 bq = *(const bf16x8*)(wq + (size_t)nt * 16 * 384 + ks * 32);
        bf16x8 bk = *(const bf16x8*)(wk + (size_t)nt * 16 * 384 + ks * 32);
        qf[0][nt] = MFMA(a0, bq, qf[0][nt]);
        qf[1][nt] = MFMA(a1, bq, qf[1][nt]);
        kf[0][nt] = MFMA(a0, bk, kf[0][nt]);
        kf[1][nt] = MFMA(a1, bk, kf[1][nt]);
      }
    }
    // write QK interleaved row [Q(64B)|K(64B)] + KT (own rows / own m-half)
#pragma unroll
    for (int mt = 0; mt < 2; ++mt)
#pragma unroll
      for (int nt = 0; nt < 2; ++nt)
#pragma unroll
        for (int rr = 0; rr < 4; ++rr) {
          int n = nb + mt * 16 + l4 * 4 + rr;
          int d = nt * 16 + l15;
          int sw = (n & 7) << 4;
          *(ushort_a*)(PB + ((n * 128 + d * 2) ^ sw)) =
              f2bf(qf[mt][nt][rr] * 0.176776695f);
          unsigned short kvv = f2bf(kf[mt][nt][rr]);
          *(ushort_a*)(PB + ((n * 128 + 64 + d * 2) ^ sw)) = kvv;
          *(ushort_a*)(KTb + ((d * 128 + n * 2) ^ ((d & 7) << 4))) = kvv;
        }
    __syncthreads();
    // scores S[n(own half)][m(all)] (K=32, 1 kstep)
    f32x4 sf[2][4] = {};
    {
      bf16x8 bkv[4];
#pragma unroll
      for (int ni = 0; ni < 4; ++ni) {
        int m = ni * 16 + l15;
        bkv[ni] = *(const bf16x8*)(PB + ((m * 128 + 64 + l4 * 16) ^ ((m & 7) << 4)));
      }
#pragma unroll
      for (int mt = 0; mt < 2; ++mt) {
        int n = nb + mt * 16 + l15;
        bf16x8 aq = *(const bf16x8*)(PB + ((n * 128 + l4 * 16) ^ ((n & 7) << 4)));
#pragma unroll
        for (int ni = 0; ni < 4; ++ni) sf[mt][ni] = MFMA(aq, bkv[ni], sf[mt][ni]);
      }
    }
    __syncthreads();  // before P overlays QK
    // softmax over m; write P (overlays QK region)
#pragma unroll
    for (int mt = 0; mt < 2; ++mt) {
#pragma unroll
      for (int rr = 0; rr < 4; ++rr) {
        float v0 = sf[mt][0][rr], v1 = sf[mt][1][rr],
              v2 = sf[mt][2][rr], v3 = sf[mt][3][rr];
        float mx = fmaxf(fmaxf(v0, v1), fmaxf(v2, v3));
        mx = fmaxf(mx, __shfl_xor(mx, 1, 64));
        mx = fmaxf(mx, __shfl_xor(mx, 2, 64));
        mx = fmaxf(mx, __shfl_xor(mx, 4, 64));
        mx = fmaxf(mx, __shfl_xor(mx, 8, 64));
        float e0 = __expf(v0 - mx), e1 = __expf(v1 - mx),
              e2 = __expf(v2 - mx), e3 = __expf(v3 - mx);
        float sm = e0 + e1 + e2 + e3;
        sm += __shfl_xor(sm, 1, 64);
        sm += __shfl_xor(sm, 2, 64);
        sm += __shfl_xor(sm, 4, 64);
        sm += __shfl_xor(sm, 8, 64);
        float rs = 1.0f / sm;
        int n = nb + mt * 16 + l4 * 4 + rr;
        int base = n * 128, sw = (n & 7) << 4;
        *(ushort_a*)(PB + ((base + l15 * 2) ^ sw))      = f2bf(e0 * rs);
        *(ushort_a*)(PB + ((base + 32 + l15 * 2) ^ sw)) = f2bf(e1 * rs);
        *(ushort_a*)(PB + ((base + 64 + l15 * 2) ^ sw)) = f2bf(e2 * rs);
        *(ushort_a*)(PB + ((base + 96 + l15 * 2) ^ sw)) = f2bf(e3 * rs);
      }
    }
    // PV: X[n(own half)][d] = P·kv (reads own P rows + shared KTb)
    f32x4 xo[2][2] = {};
#pragma unroll
    for (int ks = 0; ks < 2; ++ks) {
      bf16x8 bv[2];
#pragma unroll
      for (int nt = 0; nt < 2; ++nt) {
        int d = nt * 16 + l15;
        bv[nt] = *(const bf16x8*)(KTb + ((d * 128 + ks * 64 + l4 * 16) ^ ((d & 7) << 4)));
      }
#pragma unroll
      for (int mt = 0; mt < 2; ++mt) {
        int n = nb + mt * 16 + l15;
        bf16x8 ap = *(const bf16x8*)(PB + ((n * 128 + ks * 64 + l4 * 16) ^ ((n & 7) << 4)));
        xo[mt][0] = MFMA(ap, bv[0], xo[mt][0]);
        xo[mt][1] = MFMA(ap, bv[1], xo[mt][1]);
      }
    }
    // gate + write gated x_attn chunk into stage [64][128]
#pragma unroll
    for (int mt = 0; mt < 2; ++mt) {
#pragma unroll
      for (int rr = 0; rr < 4; ++rr) {
        float gv = __shfl(gfr[mt][rr], (lane & 48) | h, 64);
        float sg = 1.0f / (1.0f + __expf(-gv));
        int n = nb + mt * 16 + l4 * 4 + rr;
        int sw = (n & 7) << 4;
        int c0 = pair * 32 + l15;
        *(ushort_a*)(Stg + ((n * 256 + c0 * 2) ^ sw))        = f2bf(xo[mt][0][rr] * sg);
        *(ushort_a*)(Stg + ((n * 256 + (c0 + 16) * 2) ^ sw)) = f2bf(xo[mt][1][rr] * sg);
      }
    }
    __syncthreads();
    // attn-out accumulate: of += Stg(64x128) · wao[:, r*128 : r*128+128]^T
    {
      const unsigned short* wao0 =
          waoB + (size_t)(wave * 48 + l15) * 384 + r * 128 + l4 * 8;
#pragma unroll
      for (int ks = 0; ks < 4; ++ks) {
        int kb = ks * 64 + l4 * 16, sz = (l15 & 7) << 4;
        bf16x8 a0 = *(const bf16x8*)(Stg + ((l15 * 256 + kb) ^ sz));
        bf16x8 a1 = *(const bf16x8*)(Stg + (((16 + l15) * 256 + kb) ^ sz));
        bf16x8 a2 = *(const bf16x8*)(Stg + (((32 + l15) * 256 + kb) ^ sz));
        bf16x8 a3 = *(const bf16x8*)(Stg + (((48 + l15) * 256 + kb) ^ sz));
#pragma unroll
        for (int nt = 0; nt < 3; ++nt) {
          bf16x8 bw = *(const bf16x8*)(wao0 + (size_t)nt * 16 * 384 + ks * 32);
          of[0][nt] = MFMA(a0, bw, of[0][nt]);
          of[1][nt] = MFMA(a1, bw, of[1][nt]);
          of[2][nt] = MFMA(a2, bw, of[2][nt]);
          of[3][nt] = MFMA(a3, bw, of[3][nt]);
        }
      }
    }
    // no barrier needed: next round's first barrier orders region reuse
  }

  // ---- FF: 12 tiles of 128 cols; StarReLU; of += F · wfo^T ----
#pragma unroll 1
  for (int t = 0; t < 12; ++t) {
    f32x4 ffr[4] = {};
    const unsigned short* wfin =
        wfB + (size_t)(768 + t * 128 + wave * 16 + l15) * 384 + l4 * 8;
#pragma unroll 2
    for (int ks = 0; ks < 12; ++ks) {
      bf16x8 a0 = ldA(l15, ks), a1 = ldA(16 + l15, ks),
             a2 = ldA(32 + l15, ks), a3 = ldA(48 + l15, ks);
      bf16x8 bw = *(const bf16x8*)(wfin + ks * 32);
      ffr[0] = MFMA(a0, bw, ffr[0]);
      ffr[1] = MFMA(a1, bw, ffr[1]);
      ffr[2] = MFMA(a2, bw, ffr[2]);
      ffr[3] = MFMA(a3, bw, ffr[3]);
    }
    char* fb = smem + 49152 + (t & 1) * 16384;  // [64][128] bf16, row-swz
#pragma unroll
    for (int mt = 0; mt < 4; ++mt)
#pragma unroll
      for (int rr = 0; rr < 4; ++rr) {
        float v = fmaxf(ffr[mt][rr], 0.0f);
        v = ss * v * v + sbi;  // StarReLU
        int n = mt * 16 + l4 * 4 + rr;
        int cw = wave * 16 + l15;
        *(ushort_a*)(fb + ((n * 256 + cw * 2) ^ ((n & 7) << 4))) = f2bf(v);
      }
    __syncthreads();
    const unsigned short* wfo2 =
        wfoB + (size_t)(wave * 48 + l15) * 1536 + t * 128 + l4 * 8;
#pragma unroll
    for (int ks = 0; ks < 4; ++ks) {
      int kb = ks * 64 + l4 * 16, sz = (l15 & 7) << 4;
      bf16x8 a0 = *(const bf16x8*)(fb + ((l15 * 256 + kb) ^ sz));
      bf16x8 a1 = *(const bf16x8*)(fb + (((16 + l15) * 256 + kb) ^ sz));
      bf16x8 a2 = *(const bf16x8*)(fb + (((32 + l15) * 256 + kb) ^ sz));
      bf16x8 a3 = *(const bf16x8*)(fb + (((48 + l15) * 256 + kb) ^ sz));
#pragma unroll
      for (int nt = 0; nt < 3; ++nt) {
        bf16x8 bw = *(const bf16x8*)(wfo2 + (size_t)nt * 16 * 1536 + ks * 32);
        of[0][nt] = MFMA(a0, bw, of[0][nt]);
        of[1][nt] = MFMA(a1, bw, of[1][nt]);
        of[2][nt] = MFMA(a2, bw, of[2][nt]);
        of[3][nt] = MFMA(a3, bw, of[3][nt]);
      }
    }
  }

  // ---- epilogue: scatter out (fp32, NCHW), vectorized dwordx4 ----
  float* ob = out + (size_t)b * 1572864 + h0 * 64 + w0;
#pragma unroll
  for (int nt = 0; nt < 3; ++nt) {
    int col = wave * 48 + nt * 16 + l15;
    float* oc = ob + (size_t)col * 4096;
#pragma unroll
    for (int mt = 0; mt < 4; ++mt) {
      int n0 = mt * 16 + l4 * 4;  // 4 consecutive tokens -> 16B store
      *(f32x4*)(oc + (n0 >> 3) * 64 + (n0 & 7)) = of[mt][nt];
    }
  }
}

extern "C" void kernel_launch(void* const* d_in, const int* in_sizes, int n_in,
                              void* d_out, int out_size, void* d_ws, size_t ws_size,
                              hipStream_t stream) {
  const float* x   = (const float*)d_in[0];
  const float* wf  = (const float*)d_in[1];
  const float* wg  = (const float*)d_in[2];
  const float* bg  = (const float*)d_in[3];
  const float* wao = (const float*)d_in[4];
  const float* wfo = (const float*)d_in[5];
  const float* srs = (const float*)d_in[6];
  const float* srb = (const float*)d_in[7];
  unsigned short* ws = (unsigned short*)d_ws;

  prep_weights<<<6360, 256, 0, stream>>>(wf, wg, wao, wfo, ws);
  fused_main<<<1024, 512, 0, stream>>>(x, bg, srs, srb, ws, (float*)d_out);
}